// Round 1
// baseline (7164.454 us; speedup 1.0000x reference)
//
#include <hip/hip_runtime.h>

typedef unsigned short ushort_t;
typedef __attribute__((ext_vector_type(4))) float f32x4;
typedef __attribute__((ext_vector_type(8))) __bf16 bf16x8;

#define SEQ   512
#define BATCH 128
#define HID   1024
#define G4    4096
#define CHUNK 64
#define BH    (BATCH*HID)

__device__ __forceinline__ ushort_t f2bf(float f) {
  unsigned u = __float_as_uint(f);
  u += 0x7FFFu + ((u >> 16) & 1u);     // RNE
  return (ushort_t)(u >> 16);
}
__device__ __forceinline__ float bf2f(ushort_t h) {
  return __uint_as_float(((unsigned)h) << 16);
}
__device__ __forceinline__ float sigm(float x) { return 1.0f / (1.0f + __expf(-x)); }

__device__ __forceinline__ void lds16(const ushort_t* g, ushort_t* l) {
  __builtin_amdgcn_global_load_lds(
      (const __attribute__((address_space(1))) unsigned int*)g,
      (__attribute__((address_space(3))) unsigned int*)l, 16, 0, 0);
}

// ---------------- casts ----------------
__global__ void cast_f32_bf16(const float* __restrict__ in, ushort_t* __restrict__ out, int n4) {
  int i = blockIdx.x * blockDim.x + threadIdx.x;
  if (i < n4) {
    float4 v = ((const float4*)in)[i];
    union { ushort_t u[4]; uint2 v2; } o;
    o.u[0] = f2bf(v.x); o.u[1] = f2bf(v.y); o.u[2] = f2bf(v.z); o.u[3] = f2bf(v.w);
    ((uint2*)out)[i] = o.v2;
  }
}

// pW (4096 x 2048) f32 -> pWt (2048 x 4096) bf16
__global__ __launch_bounds__(256) void transpose_cast(const float* __restrict__ pw, ushort_t* __restrict__ pwt) {
  __shared__ float tile[32][33];
  int bx = blockIdx.x, by = blockIdx.y;
  int tx = threadIdx.x & 31, ty = threadIdx.x >> 5;
  for (int i = 0; i < 32; i += 8)
    tile[ty + i][tx] = pw[(size_t)(by*32 + ty + i)*2048 + bx*32 + tx];
  __syncthreads();
  for (int i = 0; i < 32; i += 8) {
    int r = ty + i;
    pwt[(size_t)(bx*32 + r)*4096 + by*32 + tx] = f2bf(tile[tx][r]);
  }
}

// b2[g*1024+j] = sum_k qW[j,k] * pb[g*1024+k]
__global__ void bias_fold(const float* __restrict__ qW, const float* __restrict__ pb, float* __restrict__ b2) {
  int r = blockIdx.x;
  int j = r & (HID-1), gb = r & ~(HID-1);
  float s = 0.f;
  for (int k = threadIdx.x; k < HID; k += 64)
    s += qW[(size_t)j*HID + k] * pb[gb + k];
  for (int off = 32; off; off >>= 1) s += __shfl_down(s, off, 64);
  if (threadIdx.x == 0) b2[r] = s;
}

// ---------------- 128x128 bf16 MFMA GEMM (m97 structure), C = A @ B^T (+bias), bf16 out
// A: rows masked by arow_mask (for block-diag qW). B row n uses k-offset (bm*128)&bko_mask.
__global__ __launch_bounds__(256) void gemm128(
    const ushort_t* __restrict__ A, int lda, unsigned arow_mask,
    const ushort_t* __restrict__ B, int ldb, unsigned bko_mask,
    const float* __restrict__ bias, ushort_t* __restrict__ C, int ldc, int K)
{
  __shared__ __align__(16) ushort_t Al[128*64];
  __shared__ __align__(16) ushort_t Bl[128*64];
  const int tid = threadIdx.x, wv = tid >> 6, ln = tid & 63;
  const int bn = blockIdx.x, bm = blockIdx.y;
  const int bko = (int)(((unsigned)(bm << 7)) & bko_mask);
  const int m0 = (wv & 1) << 6, n0 = (wv >> 1) << 6;
  f32x4 acc[4][4] = {};
  for (int k0 = 0; k0 < K; k0 += 64) {
    for (int rr = 0; rr < 4; ++rr) {
      int r0 = (rr << 5) + (wv << 3);
      unsigned ga = ((unsigned)((bm << 7) + r0 + (ln >> 3))) & arow_mask;
      lds16(A + (size_t)ga*lda + k0 + ((ln & 7) << 3), &Al[r0 << 6]);
      unsigned gbr = (unsigned)((bn << 7) + r0 + (ln >> 3));
      lds16(B + (size_t)gbr*ldb + bko + k0 + ((ln & 7) << 3), &Bl[r0 << 6]);
    }
    __syncthreads();
    for (int kk = 0; kk < 64; kk += 32) {
      const int lrow = ln & 15, lk = kk + ((ln >> 4) << 3);
      bf16x8 af[4], bfr[4];
      for (int i = 0; i < 4; ++i) af[i]  = *(const bf16x8*)&Al[((m0 + (i << 4) + lrow) << 6) + lk];
      for (int j = 0; j < 4; ++j) bfr[j] = *(const bf16x8*)&Bl[((n0 + (j << 4) + lrow) << 6) + lk];
      for (int i = 0; i < 4; ++i)
        for (int j = 0; j < 4; ++j)
          acc[i][j] = __builtin_amdgcn_mfma_f32_16x16x32_bf16(af[i], bfr[j], acc[i][j], 0, 0, 0);
    }
    __syncthreads();
  }
  for (int i = 0; i < 4; ++i)
    for (int j = 0; j < 4; ++j) {
      int col = (bn << 7) + n0 + (j << 4) + (ln & 15);
      float bv = bias ? bias[col] : 0.f;
      for (int r = 0; r < 4; ++r) {
        int row = (bm << 7) + m0 + (i << 4) + ((ln >> 4) << 2) + r;
        C[(size_t)row*ldc + col] = f2bf(acc[i][j][r] + bv);
      }
    }
}

// ---------------- per-step fused kernel ----------------
// grid 256: rblk = blockIdx&3 (32 hx rows), cblk = blockIdx>>2 (16 cols x 4 gates)
// preact = P[t] + hx @ U^T ; inner = sigmoid; f,i = sigmoid(inner), g = tanh, o = sigmoid
__global__ __launch_bounds__(256) void qlstm_step(
    const ushort_t* __restrict__ P,      // [CHUNK*128][4096] bf16 (chunk base)
    const ushort_t* __restrict__ W2,     // [4096][2048] bf16; U part = cols [1024,2048)
    const ushort_t* __restrict__ hx_in,  // [128][1024] bf16
    ushort_t* __restrict__ hx_out,
    float* __restrict__ cx,              // [128][1024] f32 persistent
    float* __restrict__ out_t,           // d_out + t*BH
    int t_local)
{
  __shared__ __align__(16) ushort_t Ab[2][32*128];
  __shared__ __align__(16) ushort_t Bb[2][64*128];
  __shared__ float sm[4][32*16];
  const int tid = threadIdx.x, wv = tid >> 6, ln = tid & 63;
  const int rblk = blockIdx.x & 3, cblk = blockIdx.x >> 2;
  f32x4 acc[2] = {};

  auto stage = [&](int b, int k0) {
    // A: 32 hx rows, [32][128] bf16, XOR-swizzled source (slot s holds col (s^ (row&7))*8)
    for (int rr = 0; rr < 2; ++rr) {
      int row  = rr*16 + wv*4 + (ln >> 4);
      int gcol = ((ln & 15) ^ (row & 7)) << 3;
      lds16(hx_in + (size_t)(rblk*32 + row)*1024 + k0 + gcol,
            &Ab[b][(rr*16 + wv*4)*128]);
    }
    // B: 64 U-rows (4 gates x 16 cols), [64][128] bf16
    for (int rr = 0; rr < 4; ++rr) {
      int lr   = rr*16 + wv*4 + (ln >> 4);
      int grow = ((lr >> 4) << 10) + cblk*16 + (lr & 15);
      int gcol = ((ln & 15) ^ (lr & 7)) << 3;
      lds16(W2 + (size_t)grow*2048 + 1024 + k0 + gcol,
            &Bb[b][(rr*16 + wv*4)*128]);
    }
  };
  auto compute = [&](int b) {
    for (int k4 = 0; k4 < 4; ++k4) {
      int slot = k4*4 + (ln >> 4);
      int ar0 = ln & 15, ar1 = 16 + (ln & 15);
      int brow = wv*16 + (ln & 15);
      bf16x8 a0 = *(const bf16x8*)&Ab[b][ar0*128 + ((slot ^ (ar0 & 7)) << 3)];
      bf16x8 a1 = *(const bf16x8*)&Ab[b][ar1*128 + ((slot ^ (ar1 & 7)) << 3)];
      bf16x8 bb = *(const bf16x8*)&Bb[b][brow*128 + ((slot ^ (brow & 7)) << 3)];
      acc[0] = __builtin_amdgcn_mfma_f32_16x16x32_bf16(a0, bb, acc[0], 0, 0, 0);
      acc[1] = __builtin_amdgcn_mfma_f32_16x16x32_bf16(a1, bb, acc[1], 0, 0, 0);
    }
  };

  stage(0, 0);
  __syncthreads();
  for (int ck = 0; ck < 8; ++ck) {             // K=1024 in BK=128 chunks, dbuf, 1 barrier/chunk
    if (ck < 7) stage((ck + 1) & 1, (ck + 1)*128);
    compute(ck & 1);
    __syncthreads();
  }

  // epilogue: inner sigmoid -> LDS exchange across gate-waves
  for (int i = 0; i < 2; ++i)
    for (int r = 0; r < 4; ++r) {
      int b_loc = i*16 + ((ln >> 4) << 2) + r;
      int gb = rblk*32 + b_loc;
      int gcol = (wv << 10) + cblk*16 + (ln & 15);
      float pv = bf2f(P[(size_t)(t_local*128 + gb)*4096 + gcol]);
      sm[wv][b_loc*16 + (ln & 15)] = sigm(acc[i][r] + pv);
    }
  __syncthreads();
  for (int e = tid; e < 512; e += 256) {
    int b_loc = e >> 4, j = e & 15;
    float fi = sigm(sm[0][e]);
    float ii = sigm(sm[1][e]);
    float gg = tanhf(sm[2][e]);
    float oo = sigm(sm[3][e]);
    size_t ci = (size_t)(rblk*32 + b_loc)*1024 + cblk*16 + j;
    float cn = fi * cx[ci] + ii * gg;
    float h  = oo * tanhf(cn);
    cx[ci] = cn;
    out_t[ci] = h;
    hx_out[ci] = f2bf(h);
  }
}

extern "C" void kernel_launch(void* const* d_in, const int* in_sizes, int n_in,
                              void* d_out, int out_size, void* d_ws, size_t ws_size,
                              hipStream_t stream) {
  const float* x  = (const float*)d_in[0];   // (512,128,1024)
  const float* pW = (const float*)d_in[1];   // (4096,2048)
  const float* pb = (const float*)d_in[2];   // (4096)
  const float* qW = (const float*)d_in[3];   // (1024,1024)
  float* out = (float*)d_out;

  char* w = (char*)d_ws;
  auto carve = [&](size_t bytes) { char* p = w; w += (bytes + 255) & ~(size_t)255; return p; };
  ushort_t* qWbf = (ushort_t*)carve((size_t)HID*HID*2);        //  2 MB
  ushort_t* pWt  = (ushort_t*)carve((size_t)2048*4096*2);      // 16 MB
  ushort_t* W2   = (ushort_t*)carve((size_t)4096*2048*2);      // 16 MB
  float*    b2   = (float*)   carve((size_t)4096*4);
  ushort_t* hx0  = (ushort_t*)carve((size_t)BH*2);
  ushort_t* hx1  = (ushort_t*)carve((size_t)BH*2);
  float*    cxws = (float*)   carve((size_t)BH*4);
  ushort_t* xbf  = (ushort_t*)carve((size_t)CHUNK*BATCH*HID*2);// 16 MB
  ushort_t* Pc   = (ushort_t*)carve((size_t)CHUNK*BATCH*G4*2); // 64 MB

  // weight folding: W2 = blockdiag(qW) @ proj_W  (bf16), b2 = qW @ b_g
  cast_f32_bf16<<<(HID*HID/4 + 255)/256, 256, 0, stream>>>(qW, qWbf, HID*HID/4);
  transpose_cast<<<dim3(64, 128), 256, 0, stream>>>(pW, pWt);
  bias_fold<<<4096, 64, 0, stream>>>(qW, pb, b2);
  gemm128<<<dim3(16, 32), 256, 0, stream>>>(qWbf, 1024, 1023u, pWt, 4096, ~1023u, nullptr, W2, 2048, 1024);

  hipMemsetAsync(hx0, 0, (size_t)BH*2, stream);
  hipMemsetAsync(cxws, 0, (size_t)BH*4, stream);

  ushort_t* hxbuf[2] = { hx0, hx1 };
  for (int c = 0; c < SEQ/CHUNK; ++c) {
    cast_f32_bf16<<<(CHUNK*BATCH*HID/4 + 255)/256, 256, 0, stream>>>(
        x + (size_t)c*CHUNK*BATCH*HID, xbf, CHUNK*BATCH*HID/4);
    // P = x_bf @ V^T + b2   (V = W2 cols [0,1024))
    gemm128<<<dim3(G4/128, CHUNK*BATCH/128), 256, 0, stream>>>(
        xbf, 1024, ~0u, W2, 2048, 0u, b2, Pc, 4096, 1024);
    for (int tl = 0; tl < CHUNK; ++tl) {
      int t = c*CHUNK + tl;
      qlstm_step<<<256, 256, 0, stream>>>(Pc, W2, hxbuf[t & 1], hxbuf[(t + 1) & 1],
                                          cxws, out + (size_t)t*BH, tl);
    }
  }
  hipMemcpyAsync(out + (size_t)SEQ*BH,      out + (size_t)(SEQ-1)*BH, (size_t)BH*4,
                 hipMemcpyDeviceToDevice, stream);
  hipMemcpyAsync(out + (size_t)SEQ*BH + BH, cxws, (size_t)BH*4,
                 hipMemcpyDeviceToDevice, stream);
}